// Round 1
// baseline (375.323 us; speedup 1.0000x reference)
//
#include <hip/hip_runtime.h>
#include <math.h>

// Problem constants (from setup_inputs): B=64, G=4999, P=50
constexpr int Bc = 64;
constexpr int Gc = 4999;
constexpr int Pc = 50;

constexpr int SORT_N = 8192;   // pow2 >= G
constexpr int SORT_T = 1024;
constexpr int ES_T   = 256;

// ---------------------------------------------------------------------------
// Kernel 1: per-sample stable descending argsort via bitonic sort on u64 keys.
// key = (~sortable_u32(val) << 32) | index  → ascending u64 sort == descending
// value, ties broken by ascending original index (matches stable argsort(-x)).
// ---------------------------------------------------------------------------
__global__ __launch_bounds__(SORT_T) void sort_kernel(
    const float* __restrict__ expr, int G,
    int* __restrict__ order, float* __restrict__ wq)
{
    __shared__ unsigned long long key[SORT_N];
    const int b = blockIdx.x;
    const int tid = threadIdx.x;
    const float* row = expr + (size_t)b * G;

    for (int i = tid; i < SORT_N; i += SORT_T) {
        unsigned long long k;
        if (i < G) {
            unsigned u = __float_as_uint(row[i]);
            u = (u & 0x80000000u) ? ~u : (u | 0x80000000u);  // monotone map
            k = ((unsigned long long)(~u) << 32) | (unsigned)i;
        } else {
            k = 0xFFFFFFFFFFFFFFFFull;  // pad sorts to the end
        }
        key[i] = k;
    }
    __syncthreads();

    for (int kk = 2; kk <= SORT_N; kk <<= 1) {
        for (int j = kk >> 1; j > 0; j >>= 1) {
            for (int i = tid; i < SORT_N; i += SORT_T) {
                int ixj = i ^ j;
                if (ixj > i) {
                    unsigned long long a = key[i];
                    unsigned long long c = key[ixj];
                    bool up = ((i & kk) == 0);
                    if ((a > c) == up) { key[i] = c; key[ixj] = a; }
                }
            }
            __syncthreads();
        }
    }

    for (int i = tid; i < G; i += SORT_T) {
        unsigned long long k = key[i];
        int idx = (int)(unsigned)(k & 0xFFFFFFFFu);
        order[(size_t)b * G + i] = idx;
        float v = row[idx];
        // |v|^0.25 == sqrt(sqrt(|v|)), ~1 ulp
        wq[(size_t)b * G + i] = sqrtf(sqrtf(fabsf(v)));
    }
}

// ---------------------------------------------------------------------------
// Kernel 2: one block per (b,p). Pathway row in LDS; chunked block-scan of
// running = cumsum(w*hit*norm - (1-hit)*inv_denom); first-occurrence argmax
// of |running|; es = running at that position (0 if size==0).
// ---------------------------------------------------------------------------
__global__ __launch_bounds__(ES_T) void es_kernel(
    const float* __restrict__ pathway,
    const int* __restrict__ order, const float* __restrict__ wq,
    float* __restrict__ out, int B, int P, int G)
{
    __shared__ float  row[Gc + 1];
    __shared__ double red[ES_T];
    __shared__ double redh[ES_T];
    __shared__ double bv[ES_T];
    __shared__ double br[ES_T];
    __shared__ int    bi[ES_T];

    const int p = blockIdx.x;
    const int b = blockIdx.y;
    const int tid = threadIdx.x;

    const float* prow = pathway + (size_t)p * G;
    for (int i = tid; i < G; i += ES_T) row[i] = prow[i];
    __syncthreads();

    const int* ordb = order + (size_t)b * G;
    const float* wqb = wq + (size_t)b * G;

    const int L = (G + ES_T - 1) / ES_T;            // 20
    const int start = tid * L;
    const int end = (start + L < G) ? (start + L) : G;

    // Pass A: s = sum(w*hit), size = sum(hit)
    double sw = 0.0;
    int sh = 0;
    for (int i = start; i < end; ++i) {
        if (row[ordb[i]] > 0.0f) { sw += (double)wqb[i]; sh++; }
    }
    red[tid] = sw;
    redh[tid] = (double)sh;
    __syncthreads();
    for (int off = ES_T / 2; off > 0; off >>= 1) {
        if (tid < off) { red[tid] += red[tid + off]; redh[tid] += redh[tid + off]; }
        __syncthreads();
    }
    const double s_total = red[0];
    const double psize   = redh[0];
    __syncthreads();  // everyone read red[0] before reuse

    const double norm      = (s_total > 0.0) ? 1.0 / s_total : 1.0;
    const double inv_denom = 1.0 / fmax((double)G - psize, 1.0);

    // Pass B: chunk sums of d_i
    double csum = 0.0;
    for (int i = start; i < end; ++i) {
        csum += (row[ordb[i]] > 0.0f) ? (double)wqb[i] * norm : -inv_denom;
    }
    red[tid] = csum;
    __syncthreads();
    // Hillis-Steele inclusive scan over 256 chunk sums
    for (int off = 1; off < ES_T; off <<= 1) {
        double v = 0.0;
        if (tid >= off) v = red[tid - off];
        __syncthreads();
        if (tid >= off) red[tid] += v;
        __syncthreads();
    }
    const double prefix = red[tid] - csum;  // exclusive prefix for this chunk

    // Pass C: walk chunk, track first-occurrence max of |running|
    double running = prefix;
    double bestv = -1.0, bestr = 0.0;
    int besti = 0x7FFFFFFF;
    for (int i = start; i < end; ++i) {
        running += (row[ordb[i]] > 0.0f) ? (double)wqb[i] * norm : -inv_denom;
        double a = fabs(running);
        if (a > bestv) { bestv = a; bestr = running; besti = i; }
    }
    bv[tid] = bestv; br[tid] = bestr; bi[tid] = besti;
    __syncthreads();
    for (int off = ES_T / 2; off > 0; off >>= 1) {
        if (tid < off) {
            bool take = (bv[tid + off] > bv[tid]) ||
                        (bv[tid + off] == bv[tid] && bi[tid + off] < bi[tid]);
            if (take) {
                bv[tid] = bv[tid + off];
                br[tid] = br[tid + off];
                bi[tid] = bi[tid + off];
            }
        }
        __syncthreads();
    }

    if (tid == 0) {
        float es = (psize > 0.0) ? (float)br[0] : 0.0f;
        out[(size_t)b * P + p] = es;
    }
}

extern "C" void kernel_launch(void* const* d_in, const int* in_sizes, int n_in,
                              void* d_out, int out_size, void* d_ws, size_t ws_size,
                              hipStream_t stream) {
    const float* expr    = (const float*)d_in[0];   // [B, G]
    const float* pathway = (const float*)d_in[1];   // [P, G]
    float* out = (float*)d_out;                     // [B, P]

    const int B = Bc, G = Gc, P = Pc;

    // workspace layout: order [B*G] int, wq [B*G] float
    int*   order = (int*)d_ws;
    float* wq    = (float*)((char*)d_ws + (size_t)B * G * sizeof(int));

    sort_kernel<<<dim3(B), dim3(SORT_T), 0, stream>>>(expr, G, order, wq);
    es_kernel<<<dim3(P, B), dim3(ES_T), 0, stream>>>(pathway, order, wq, out, B, P, G);
}

// Round 2
// 223.632 us; speedup vs baseline: 1.6783x; 1.6783x over previous
//
#include <hip/hip_runtime.h>
#include <math.h>

typedef unsigned long long ull;

// Problem constants (from setup_inputs): B=64, G=4999, P=50
constexpr int Bc = 64;
constexpr int Gc = 4999;
constexpr int Pc = 50;

constexpr int SORT_N = 8192;   // pow2 >= G
constexpr int SORT_T = 1024;   // threads
constexpr int EPT    = 8;      // elements per thread (SORT_N / SORT_T)
constexpr int LPW    = 79;     // ceil(G/64) elements per lane in es kernel

__device__ __forceinline__ ull shfl_xor64(ull v, int lm) {
    int lo = __shfl_xor((int)(unsigned)(v & 0xFFFFFFFFull), lm, 64);
    int hi = __shfl_xor((int)(unsigned)(v >> 32), lm, 64);
    return ((ull)(unsigned)hi << 32) | (unsigned)lo;
}

// ---------------------------------------------------------------------------
// Kernel 0: pack pathway membership bits. pbits[g] bit p = pathway[p][g] > 0.
// ---------------------------------------------------------------------------
__global__ void pack_kernel(const float* __restrict__ pathway,
                            ull* __restrict__ pbits, int P, int G)
{
    int g = blockIdx.x * 256 + threadIdx.x;
    if (g >= G) return;
    ull m = 0;
    for (int p = 0; p < P; ++p)
        if (pathway[(size_t)p * G + g] > 0.0f) m |= (1ull << p);
    pbits[g] = m;
}

// ---------------------------------------------------------------------------
// Kernel 1: per-sample stable descending argsort, register/shuffle bitonic.
// key = (~m)<<32 | idx, m = monotone map of float → ascending u64 sort ==
// descending value, ties by ascending index (== stable argsort(-x)).
// 8 elems/thread in regs; j<=4 in-register, j=8..256 via shfl_xor (intra-wave,
// no barrier), j>=512 via LDS. Epilogue writes wq (|v|^0.25 recovered from
// the key arithmetically) and mask (pbits gather) in sorted order.
// ---------------------------------------------------------------------------
__global__ __launch_bounds__(SORT_T) void sort_kernel(
    const float* __restrict__ expr, const ull* __restrict__ pbits, int G,
    float* __restrict__ wq, ull* __restrict__ mask)
{
    __shared__ ull key[SORT_N];
    const int b = blockIdx.x;
    const int tid = threadIdx.x;
    const int base = tid * EPT;
    const float* row = expr + (size_t)b * G;

    ull r[EPT];
#pragma unroll
    for (int o = 0; o < EPT; ++o) {
        int i = base + o;
        if (i < G) {
            unsigned u = __float_as_uint(row[i]);
            unsigned m = (u >> 31) ? ~u : (u | 0x80000000u);
            r[o] = ((ull)(~m) << 32) | (unsigned)i;
        } else {
            r[o] = 0xFFFFFFFFFFFFFFFFull;
        }
    }

    // ---- Phase 1: kk = 2..512 entirely in registers + wave shuffles ----
#pragma unroll
    for (int kk = 2; kk <= 512; kk <<= 1) {
        // shuffle stages: j = kk/2 .. 8 (partner thread tid^(j/8), same wave)
#pragma unroll
        for (int j = kk >> 1; j >= 8; j >>= 1) {
            int lm = j >> 3;
            bool lower = ((tid & lm) == 0);
            bool up = ((base & kk) == 0);        // kk>=16 here: const per thread
            bool takeMin = (lower == up);
#pragma unroll
            for (int o = 0; o < EPT; ++o) {
                ull c = shfl_xor64(r[o], lm);
                ull mn = (r[o] < c) ? r[o] : c;
                ull mx = (r[o] < c) ? c : r[o];
                r[o] = takeMin ? mn : mx;
            }
        }
        // register stages: j = min(kk/2,4) .. 1
#pragma unroll
        for (int j = 4; j >= 1; j >>= 1) {
            if (j < kk) {
#pragma unroll
                for (int o = 0; o < EPT; ++o) {
                    if ((o & j) == 0) {
                        bool up = (((base + o) & kk) == 0);
                        ull a = r[o], c = r[o | j];
                        if ((a > c) == up) { r[o] = c; r[o | j] = a; }
                    }
                }
            }
        }
    }

    // ---- Phase 2: kk = 1024..8192; j>=512 via LDS, tail local ----
#pragma unroll
    for (int o = 0; o < EPT; ++o) key[base + o] = r[o];
    __syncthreads();

#pragma unroll
    for (int kk = 1024; kk <= SORT_N; kk <<= 1) {
#pragma unroll
        for (int j = kk >> 1; j >= 512; j >>= 1) {
#pragma unroll
            for (int t = tid; t < SORT_N / 2; t += SORT_T) {
                int i = ((t & ~(j - 1)) << 1) | (t & (j - 1));
                int ix = i | j;
                ull a = key[i], c = key[ix];
                bool up = ((i & kk) == 0);
                if ((a > c) == up) { key[i] = c; key[ix] = a; }
            }
            __syncthreads();
        }
        // local tail: j = 256..1
#pragma unroll
        for (int o = 0; o < EPT; ++o) r[o] = key[base + o];
#pragma unroll
        for (int j = 256; j >= 8; j >>= 1) {
            int lm = j >> 3;
            bool lower = ((tid & lm) == 0);
            bool up = ((base & kk) == 0);
            bool takeMin = (lower == up);
#pragma unroll
            for (int o = 0; o < EPT; ++o) {
                ull c = shfl_xor64(r[o], lm);
                ull mn = (r[o] < c) ? r[o] : c;
                ull mx = (r[o] < c) ? c : r[o];
                r[o] = takeMin ? mn : mx;
            }
        }
#pragma unroll
        for (int j = 4; j >= 1; j >>= 1) {
#pragma unroll
            for (int o = 0; o < EPT; ++o) {
                if ((o & j) == 0) {
                    bool up = (((base + o) & kk) == 0);
                    ull a = r[o], c = r[o | j];
                    if ((a > c) == up) { r[o] = c; r[o | j] = a; }
                }
            }
        }
        if (kk < SORT_N) {
#pragma unroll
            for (int o = 0; o < EPT; ++o) key[base + o] = r[o];
            __syncthreads();
        }
    }

    // ---- Epilogue: registers hold final sorted keys at positions base+o ----
#pragma unroll
    for (int o = 0; o < EPT; ++o) {
        int i = base + o;
        if (i < G) {
            ull k = r[o];
            int idx = (int)(unsigned)(k & 0xFFFFFFFFu);
            unsigned m = ~((unsigned)(k >> 32));
            unsigned absbits = ((m >> 31) ? m : ~m) & 0x7FFFFFFFu;
            float av = __uint_as_float(absbits);
            wq[(size_t)b * G + i] = sqrtf(sqrtf(av));   // |v|^0.25
            mask[(size_t)b * G + i] = pbits[idx];
        }
    }
}

// ---------------------------------------------------------------------------
// Kernel 2: one wave per (b,p). Lanes own 79-elem contiguous chunks.
// Pass A: per-chunk (sum w*hit, #hit) + butterfly reduce → norm, inv_denom.
// Chunk scan value derived algebraically; __shfl_up scan gives prefixes.
// Pass C: walk chunk tracking first-occurrence argmax of |running|;
// butterfly arg-reduce. No LDS, no barriers.
// ---------------------------------------------------------------------------
__global__ __launch_bounds__(256) void es_kernel(
    const float* __restrict__ wq, const ull* __restrict__ mask,
    float* __restrict__ out, int B, int P, int G)
{
    const int lane = threadIdx.x & 63;
    const int waveid = threadIdx.x >> 6;
    const int p = blockIdx.x * 4 + waveid;
    const int b = blockIdx.y;
    if (p >= P) return;

    const float* wqb = wq + (size_t)b * G;
    const ull*   mb  = mask + (size_t)b * G;
    const ull pb = 1ull << p;

    const int start = lane * LPW;
    const int end = (start + LPW < G) ? (start + LPW) : G;
    const int cnt = end - start;

    // Pass A
    double sw = 0.0;
    int sh = 0;
    for (int i = start; i < end; ++i) {
        if (mb[i] & pb) { sw += (double)wqb[i]; sh++; }
    }
    double swt = sw;
    int sht = sh;
#pragma unroll
    for (int off = 1; off < 64; off <<= 1) {
        swt += __shfl_xor(swt, off, 64);
        sht += __shfl_xor(sht, off, 64);
    }
    const double norm      = (swt > 0.0) ? 1.0 / swt : 1.0;
    const double inv_denom = 1.0 / fmax((double)(G - sht), 1.0);

    // Chunk sum (algebraic, no second read) + wave inclusive scan
    double csum = sw * norm - (double)(cnt - sh) * inv_denom;
    double x = csum;
#pragma unroll
    for (int off = 1; off < 64; off <<= 1) {
        double v = __shfl_up(x, off, 64);
        if (lane >= off) x += v;
    }
    double running = x - csum;   // exclusive prefix for this chunk

    // Pass C
    double bestv = -1.0, bestr = 0.0;
    int besti = 0x7FFFFFFF;
    for (int i = start; i < end; ++i) {
        running += (mb[i] & pb) ? (double)wqb[i] * norm : -inv_denom;
        double a = fabs(running);
        if (a > bestv) { bestv = a; bestr = running; besti = i; }
    }
#pragma unroll
    for (int off = 1; off < 64; off <<= 1) {
        double ov = __shfl_xor(bestv, off, 64);
        double orr = __shfl_xor(bestr, off, 64);
        int    oi = __shfl_xor(besti, off, 64);
        if (ov > bestv || (ov == bestv && oi < besti)) {
            bestv = ov; bestr = orr; besti = oi;
        }
    }

    if (lane == 0) {
        out[(size_t)b * P + p] = (sht > 0) ? (float)bestr : 0.0f;
    }
}

extern "C" void kernel_launch(void* const* d_in, const int* in_sizes, int n_in,
                              void* d_out, int out_size, void* d_ws, size_t ws_size,
                              hipStream_t stream) {
    const float* expr    = (const float*)d_in[0];   // [B, G]
    const float* pathway = (const float*)d_in[1];   // [P, G]
    float* out = (float*)d_out;                     // [B, P]

    const int B = Bc, G = Gc, P = Pc;

    // workspace layout: pbits [G] u64 | wq [B*G] f32 | mask [B*G] u64
    char* ws = (char*)d_ws;
    ull*   pbits = (ull*)ws;                              // 40 KB
    float* wq    = (float*)(ws + 40960);                  // 1.28 MB
    ull*   mask  = (ull*)(ws + 40960 + (size_t)B * G * sizeof(float));  // 2.56 MB

    pack_kernel<<<dim3((G + 255) / 256), dim3(256), 0, stream>>>(pathway, pbits, P, G);
    sort_kernel<<<dim3(B), dim3(SORT_T), 0, stream>>>(expr, pbits, G, wq, mask);
    es_kernel<<<dim3((P + 3) / 4, B), dim3(256), 0, stream>>>(wq, mask, out, B, P, G);
}

// Round 3
// 134.810 us; speedup vs baseline: 2.7841x; 1.6589x over previous
//
#include <hip/hip_runtime.h>
#include <math.h>

typedef unsigned long long ull;

// Problem constants (from setup_inputs): B=64, G=4999, P=50
constexpr int Bc = 64;
constexpr int Gc = 4999;
constexpr int Pc = 50;

constexpr int RUN  = 1024;           // elements per sorted run
constexpr int NRUN = 5;              // runs per row (5*1024 = 5120 >= G)
constexpr int NPAD = NRUN * RUN;
constexpr ull PADKEY = 0xFFFFFFFFFFFFFFFFull;
constexpr int LPW = 79;              // ceil(G/64) elements per lane in es
constexpr int ES_WAVES = 8;

__device__ __forceinline__ ull shfl_xor64(ull v, int lm) {
    int lo = __shfl_xor((int)(unsigned)(v & 0xFFFFFFFFull), lm, 64);
    int hi = __shfl_xor((int)(unsigned)(v >> 32), lm, 64);
    return ((ull)(unsigned)hi << 32) | (unsigned)lo;
}

// ---------------------------------------------------------------------------
// Kernel 0: pack pathway membership bits. pbits[g] bit p = pathway[p][g] > 0.
// ---------------------------------------------------------------------------
__global__ void pack_kernel(const float* __restrict__ pathway,
                            ull* __restrict__ pbits, int P, int G)
{
    int g = blockIdx.x * 256 + threadIdx.x;
    if (g >= G) return;
    ull m = 0;
    for (int p = 0; p < P; ++p)
        if (pathway[(size_t)p * G + g] > 0.0f) m |= (1ull << p);
    pbits[g] = m;
}

// ---------------------------------------------------------------------------
// Kernel 1: sort one 1024-element chunk of one row. 256 threads, 4 elems each.
// key = (~m)<<32 | idx (unique): ascending u64 == descending value, stable.
// Register stages j<=2, wave-shuffle stages j=4..128, LDS stages j=256,512.
// ---------------------------------------------------------------------------
__global__ __launch_bounds__(256) void chunk_sort(
    const float* __restrict__ expr, ull* __restrict__ runs, int G)
{
    __shared__ ull key[RUN];
    const int r = blockIdx.x, b = blockIdx.y, tid = threadIdx.x;
    const int base = tid * 4;
    const float* row = expr + (size_t)b * G;

    ull v[4];
#pragma unroll
    for (int o = 0; o < 4; ++o) {
        int i = r * RUN + base + o;
        if (i < G) {
            unsigned u = __float_as_uint(row[i]);
            unsigned m = (u >> 31) ? ~u : (u | 0x80000000u);  // monotone map
            v[o] = ((ull)(~m) << 32) | (unsigned)i;
        } else {
            v[o] = PADKEY;
        }
    }

    for (int kk = 2; kk <= RUN; kk <<= 1) {
        const int j0 = kk >> 1;
        // LDS stages: j >= 256 (cross-wave)
        if (j0 >= 256) {
#pragma unroll
            for (int o = 0; o < 4; ++o) key[base + o] = v[o];
            __syncthreads();
            for (int j = j0; j >= 256; j >>= 1) {
#pragma unroll
                for (int t = tid; t < RUN / 2; t += 256) {
                    int i  = ((t & ~(j - 1)) << 1) | (t & (j - 1));
                    int ix = i | j;
                    ull a = key[i], c = key[ix];
                    bool up = ((i & kk) == 0);
                    if ((a > c) == up) { key[i] = c; key[ix] = a; }
                }
                __syncthreads();
            }
#pragma unroll
            for (int o = 0; o < 4; ++o) v[o] = key[base + o];
        }
        // wave-shuffle stages: j = min(j0,128) .. 4 (partner tid^(j/4), same wave)
        int jstart = (j0 > 128) ? 128 : j0;
        for (int j = jstart; j >= 4; j >>= 1) {
            int lm = j >> 2;
            bool takeMin = (((tid & lm) == 0) == ((base & kk) == 0));
#pragma unroll
            for (int o = 0; o < 4; ++o) {
                ull c = shfl_xor64(v[o], lm);
                ull mn = (v[o] < c) ? v[o] : c;
                ull mx = (v[o] < c) ? c : v[o];
                v[o] = takeMin ? mn : mx;
            }
        }
        // register stages: j = 2, 1
#pragma unroll
        for (int j = 2; j >= 1; j >>= 1) {
            if (j < kk) {
#pragma unroll
                for (int o = 0; o < 4; ++o) {
                    if ((o & j) == 0) {
                        bool up = (((base + o) & kk) == 0);
                        ull a = v[o], c = v[o | j];
                        if ((a > c) == up) { v[o] = c; v[o | j] = a; }
                    }
                }
            }
        }
    }

    ull* dst = runs + ((size_t)b * NRUN + r) * RUN;
#pragma unroll
    for (int o = 0; o < 4; ++o) dst[base + o] = v[o];
}

// ---------------------------------------------------------------------------
// Kernel 2: merge-by-rank. Block (r,b): own run's element at position q has
// global rank = q + sum over other 4 runs of countLess(key) (binary search in
// LDS). Unique keys -> rank is a bijection onto [0, G). Scatter wq + sorted
// gene index.
// ---------------------------------------------------------------------------
__global__ __launch_bounds__(256) void rank_scatter(
    const ull* __restrict__ runs,
    float* __restrict__ wqout, unsigned short* __restrict__ sidxout, int G)
{
    __shared__ ull other[4][RUN];   // 32 KB
    const int r = blockIdx.x, b = blockIdx.y, tid = threadIdx.x;
    const ull* rowruns = runs + (size_t)b * NPAD;

    int k = 0;
    for (int rr = 0; rr < NRUN; ++rr) {
        if (rr == r) continue;
        for (int i = tid; i < RUN; i += 256) other[k][i] = rowruns[rr * RUN + i];
        ++k;
    }
    __syncthreads();

#pragma unroll
    for (int o = 0; o < 4; ++o) {
        const int q = o * 256 + tid;               // own-run rank (coalesced)
        const ull keyv = rowruns[r * RUN + q];
        if (keyv == PADKEY) continue;              // padding sorts to the end
        int rank = q;
#pragma unroll
        for (int kk2 = 0; kk2 < 4; ++kk2) {
            int pos = 0;
#pragma unroll
            for (int s = RUN; s >= 1; s >>= 1) {
                int np = pos + s;
                if (np <= RUN && other[kk2][np - 1] < keyv) pos = np;
            }
            rank += pos;                           // # elements < keyv
        }
        // decode value -> |v|^0.25 ; low bits -> original gene index
        int idx = (int)(unsigned)(keyv & 0xFFFFFFFFu);
        unsigned m = ~((unsigned)(keyv >> 32));
        unsigned absbits = ((m >> 31) ? m : ~m) & 0x7FFFFFFFu;
        float av = __uint_as_float(absbits);
        wqout[(size_t)b * G + rank] = sqrtf(sqrtf(av));
        sidxout[(size_t)b * G + rank] = (unsigned short)idx;
    }
}

// ---------------------------------------------------------------------------
// Kernel 3: enrichment scores. Block = 512 threads (8 waves) handles one b and
// 8 pathways; stages wq/sidx/pbits into LDS once (coalesced), then each wave
// runs the contiguous-chunk scan entirely from LDS. No global gathers.
// ---------------------------------------------------------------------------
__global__ __launch_bounds__(512) void es_kernel(
    const float* __restrict__ wq, const unsigned short* __restrict__ sidx,
    const ull* __restrict__ pbits, float* __restrict__ out, int B, int P, int G)
{
    __shared__ ull            spb[Gc];   // 39992 B
    __shared__ float          swq[Gc];   // 19996 B
    __shared__ unsigned short ssx[Gc];   //  9998 B  (~70 KB total)

    const int tid = threadIdx.x;
    const int b = blockIdx.y;

    for (int i = tid; i < G; i += 512) {
        swq[i] = wq[(size_t)b * G + i];
        ssx[i] = sidx[(size_t)b * G + i];
        spb[i] = pbits[i];
    }
    __syncthreads();

    const int lane = tid & 63;
    const int w = tid >> 6;
    const int p = blockIdx.x * ES_WAVES + w;
    if (p >= P) return;

    const int start = lane * LPW;
    const int end = (start + LPW < G) ? (start + LPW) : G;
    const int cnt = end - start;

    // Pass A: per-chunk (sum w*hit, #hit), butterfly reduce
    double sw = 0.0;
    int sh = 0;
    for (int i = start; i < end; ++i) {
        if ((spb[ssx[i]] >> p) & 1ull) { sw += (double)swq[i]; sh++; }
    }
    double swt = sw;
    int sht = sh;
#pragma unroll
    for (int off = 1; off < 64; off <<= 1) {
        swt += __shfl_xor(swt, off, 64);
        sht += __shfl_xor(sht, off, 64);
    }
    const double norm      = (swt > 0.0) ? 1.0 / swt : 1.0;
    const double inv_denom = 1.0 / fmax((double)(G - sht), 1.0);

    // Chunk sum (algebraic) + wave inclusive scan -> exclusive prefix
    double csum = sw * norm - (double)(cnt - sh) * inv_denom;
    double x = csum;
#pragma unroll
    for (int off = 1; off < 64; off <<= 1) {
        double vv = __shfl_up(x, off, 64);
        if (lane >= off) x += vv;
    }
    double running = x - csum;

    // Pass C: walk chunk, first-occurrence argmax of |running|
    double bestv = -1.0, bestr = 0.0;
    int besti = 0x7FFFFFFF;
    for (int i = start; i < end; ++i) {
        running += ((spb[ssx[i]] >> p) & 1ull) ? (double)swq[i] * norm : -inv_denom;
        double a = fabs(running);
        if (a > bestv) { bestv = a; bestr = running; besti = i; }
    }
#pragma unroll
    for (int off = 1; off < 64; off <<= 1) {
        double ov  = __shfl_xor(bestv, off, 64);
        double orr = __shfl_xor(bestr, off, 64);
        int    oi  = __shfl_xor(besti, off, 64);
        if (ov > bestv || (ov == bestv && oi < besti)) {
            bestv = ov; bestr = orr; besti = oi;
        }
    }

    if (lane == 0) {
        out[(size_t)b * P + p] = (sht > 0) ? (float)bestr : 0.0f;
    }
}

extern "C" void kernel_launch(void* const* d_in, const int* in_sizes, int n_in,
                              void* d_out, int out_size, void* d_ws, size_t ws_size,
                              hipStream_t stream) {
    const float* expr    = (const float*)d_in[0];   // [B, G]
    const float* pathway = (const float*)d_in[1];   // [P, G]
    float* out = (float*)d_out;                     // [B, P]

    const int B = Bc, G = Gc, P = Pc;

    // workspace layout (bytes):
    //   pbits ull[G]        @ 0        (40960 reserved)
    //   runs  ull[B*NPAD]   @ 40960    (2621440)
    //   wq    f32[B*G]      @ 2662400  (1279744)
    //   sidx  u16[B*G]      @ 3942144  (639872)     total ~4.6 MB
    char* ws = (char*)d_ws;
    ull*            pbits = (ull*)ws;
    ull*            runs  = (ull*)(ws + 40960);
    float*          wqa   = (float*)(ws + 2662400);
    unsigned short* sidx  = (unsigned short*)(ws + 3942144);

    pack_kernel<<<dim3((G + 255) / 256), dim3(256), 0, stream>>>(pathway, pbits, P, G);
    chunk_sort<<<dim3(NRUN, B), dim3(256), 0, stream>>>(expr, runs, G);
    rank_scatter<<<dim3(NRUN, B), dim3(256), 0, stream>>>(runs, wqa, sidx, G);
    es_kernel<<<dim3((P + ES_WAVES - 1) / ES_WAVES, B), dim3(512), 0, stream>>>(
        wqa, sidx, pbits, out, B, P, G);
}